// Round 8
// baseline (970.428 us; speedup 1.0000x reference)
//
#include <hip/hip_runtime.h>
#include <hip/hip_bf16.h>
#include <cstdint>
#include <cstddef>

#define EDIM 1024
#define FDIM 4096
#define BDIM 4
#define SDIM 2048
#define MTOK (BDIM * SDIM)   // 8192 token rows
#define PLD 4096             // bf16 leading dim inside the 8KB fp32 score rows

typedef __bf16 bf16_t;
typedef __bf16 bf16x8 __attribute__((ext_vector_type(8)));
typedef float f32x4 __attribute__((ext_vector_type(4)));

__device__ __forceinline__ void gload_lds16(const void* g, void* l) {
  __builtin_amdgcn_global_load_lds(
      (const __attribute__((address_space(1))) void*)g,
      (__attribute__((address_space(3))) void*)l, 16, 0, 0);
}

__device__ __forceinline__ unsigned short bfbits(float f) {
  bf16_t h = (bf16_t)f;
  return __builtin_bit_cast(unsigned short, h);
}

// m204 bijective XCD remap of the flattened grid id (8 XCDs on MI355X).
// Pure permutation of blocks -> correctness-independent of HW mapping.
__device__ __forceinline__ void xcd_remap(int& bx, int& by, int& bz) {
  const int gx = gridDim.x, gy = gridDim.y;
  const int nwg = gx * gy * gridDim.z;
  int id = blockIdx.x + gx * (blockIdx.y + gy * blockIdx.z);
  const int q = nwg >> 3, r = nwg & 7;
  const int xcd = id & 7, off = id >> 3;
  id = (xcd < r ? xcd * (q + 1) : r * (q + 1) + (xcd - r) * q) + off;
  bx = id % gx;
  const int t = id / gx;
  by = t % gy;
  bz = t / gy;
}

// ---------------------------------------------------------------------------
// NT GEMM: C[M,N] = alpha * A[M,K] @ B[N,K]^T (+bias) (+res) (+relu)
// A, B bf16 row-major (K-contiguous, arbitrary leading dim). 128x128 tile,
// BK=64, 4 waves (2x2), each wave 64x64 via 4x4 frags of 16x16x32 MFMA.
// m97-style global_load_lds width-16 staging, linear LDS.
// DBUF=false: 2-barrier loop (4 blocks/CU capable, for grid-rich dispatches).
// DBUF=true : T3-minimum 2-phase double-buffer, one barrier per K-step
//   (64KB LDS -> 2 blocks/CU; used where grid limits to <=2/CU anyway).
//   Race-freedom: all ds_reads of buf[cur] are lgkmcnt-waited before the
//   iteration's MFMAs, which precede the barrier; STAGE(t+1) writes only
//   buf[cur^1]; the compiler-emitted vmcnt(0) before s_barrier drains the
//   staging loads so the buffer is ready when cur flips.
// z-grid batches with strides sA/sB/sC. CSKIP: skip blocks above causal
// diagonal. CKLIM: clamp K-loop to m0+128 (PV with causal-zeroed P).
// res/C not __restrict__: used in-place (res==C), 1 reader/writer per elem.
// ---------------------------------------------------------------------------
template <typename OutT, bool BIAS, bool RES, bool RELU, bool CSKIP,
          bool CKLIM, bool DBUF>
__global__ __launch_bounds__(256, 2) void gemm_nt(
    const bf16_t* __restrict__ A, const bf16_t* __restrict__ Bm,
    const float* __restrict__ bias, const float* res,
    OutT* C, int N, int K, int lda, int ldb, int ldc,
    long long sA, long long sB, long long sC, float alpha) {
  int bn, bm, bz;
  xcd_remap(bn, bm, bz);
  const int m0 = bm * 128, n0 = bn * 128;
  if constexpr (CSKIP) {
    if (n0 > m0 + 127) return;
  }
  A += (size_t)bz * sA;
  Bm += (size_t)bz * sB;
  C += (size_t)bz * sC;

  __shared__ __align__(16) bf16_t As[DBUF ? 2 : 1][128][64];
  __shared__ __align__(16) bf16_t Bs[DBUF ? 2 : 1][128][64];

  const int tid = threadIdx.x;
  const int lane = tid & 63;
  const int wid = tid >> 6;
  const int wr = (wid >> 1) * 64;  // wave row offset in tile
  const int wc = (wid & 1) * 64;   // wave col offset in tile
  const int lr = lane & 15;        // fragment row/col
  const int lk = (lane >> 4) * 8;  // fragment k offset

  f32x4 acc[4][4] = {};

  int Keff = K;
  if constexpr (CKLIM) {
    const int kl = m0 + 128;
    Keff = kl < K ? kl : K;
  }
  const int nkt = Keff >> 6;

  // staging: 128x64 bf16 tile; wave-uniform LDS base + lane*16B (m104 rule)
  const int se = tid * 8;     // element offset within tile (row-major)
  const int sr = se >> 6;     // row 0..31
  const int sc = se & 63;     // col (multiple of 8)

  auto stage = [&](int buf, int kt) {
    const int k0 = kt << 6;
    const bf16_t* Ag = A + (size_t)(m0 + sr) * lda + k0 + sc;
    const bf16_t* Bg = Bm + (size_t)(n0 + sr) * ldb + k0 + sc;
#pragma unroll
    for (int it = 0; it < 4; ++it) {
      gload_lds16(Ag + (size_t)it * 32 * lda, &As[buf][sr + it * 32][sc]);
      gload_lds16(Bg + (size_t)it * 32 * ldb, &Bs[buf][sr + it * 32][sc]);
    }
  };
  auto compute = [&](int buf) {
#pragma unroll
    for (int kk = 0; kk < 2; ++kk) {
      bf16x8 af[4], bfr[4];
#pragma unroll
      for (int i = 0; i < 4; ++i)
        af[i] = *(const bf16x8*)&As[buf][wr + i * 16 + lr][kk * 32 + lk];
#pragma unroll
      for (int i = 0; i < 4; ++i)
        bfr[i] = *(const bf16x8*)&Bs[buf][wc + i * 16 + lr][kk * 32 + lk];
#pragma unroll
      for (int mi = 0; mi < 4; ++mi)
#pragma unroll
        for (int ni = 0; ni < 4; ++ni)
          acc[mi][ni] = __builtin_amdgcn_mfma_f32_16x16x32_bf16(
              af[mi], bfr[ni], acc[mi][ni], 0, 0, 0);
    }
  };

  if constexpr (DBUF) {
    stage(0, 0);
    __syncthreads();  // vmcnt(0)+barrier: buf0 ready
    int cur = 0;
    for (int kt = 0; kt < nkt - 1; ++kt) {
      stage(cur ^ 1, kt + 1);  // prefetch flies under this tile's MFMAs
      compute(cur);
      __syncthreads();  // drains prefetch; next buffer ready
      cur ^= 1;
    }
    compute(cur);  // last tile, no prefetch
  } else {
    for (int kt = 0; kt < nkt; ++kt) {
      stage(0, kt);
      __syncthreads();
      compute(0);
      __syncthreads();
    }
  }

  // epilogue: C/D layout col=lane&15, row=(lane>>4)*4+reg  [m89/m91]
  const int rbase = (lane >> 4) * 4;
#pragma unroll
  for (int mi = 0; mi < 4; ++mi) {
#pragma unroll
    for (int ni = 0; ni < 4; ++ni) {
      const int gc = n0 + wc + ni * 16 + lr;
      float bv = 0.0f;
      if constexpr (BIAS) bv = bias[gc];
#pragma unroll
      for (int j = 0; j < 4; ++j) {
        const int gr = m0 + wr + mi * 16 + rbase + j;
        float v = acc[mi][ni][j] * alpha + bv;
        if constexpr (RES) v += res[(size_t)gr * ldc + gc];
        if constexpr (RELU) v = fmaxf(v, 0.0f);
        C[(size_t)gr * ldc + gc] = (OutT)v;
      }
    }
  }
}

// ---------------------------------------------------------------------------
// LayerNorm over last dim (E=1024), fp32 in -> bf16 out. 1 block / row.
// ---------------------------------------------------------------------------
__global__ __launch_bounds__(256) void ln_kernel(const float* __restrict__ x,
                                                 const float* __restrict__ g,
                                                 const float* __restrict__ be,
                                                 bf16_t* __restrict__ y) {
  const int row = blockIdx.x;
  const int t = threadIdx.x;
  const float4 v = ((const float4*)(x + (size_t)row * EDIM))[t];
  float s = v.x + v.y + v.z + v.w;
  float s2 = v.x * v.x + v.y * v.y + v.z * v.z + v.w * v.w;
#pragma unroll
  for (int o = 32; o > 0; o >>= 1) {
    s += __shfl_xor(s, o, 64);
    s2 += __shfl_xor(s2, o, 64);
  }
  __shared__ float red[8];
  const int wid = t >> 6;
  if ((t & 63) == 0) {
    red[wid] = s;
    red[4 + wid] = s2;
  }
  __syncthreads();
  s = red[0] + red[1] + red[2] + red[3];
  s2 = red[4] + red[5] + red[6] + red[7];
  const float mu = s * (1.0f / EDIM);
  const float var = s2 * (1.0f / EDIM) - mu * mu;
  const float rs = rsqrtf(var + 1e-5f);
  const float4 gg = ((const float4*)g)[t];
  const float4 bb = ((const float4*)be)[t];
  ushort4 o4;
  o4.x = bfbits((v.x - mu) * rs * gg.x + bb.x);
  o4.y = bfbits((v.y - mu) * rs * gg.y + bb.y);
  o4.z = bfbits((v.z - mu) * rs * gg.z + bb.z);
  o4.w = bfbits((v.w - mu) * rs * gg.w + bb.w);
  ((ushort4*)(y + (size_t)row * EDIM))[t] = o4;
}

// ---------------------------------------------------------------------------
// Row softmax over S=2048 cols, fp32 scores -> bf16 probs written IN-PLACE
// into the first 4KB of the same 8KB score row (bf16 ld PLD=4096). All
// score reads are in registers before the writes; block i touches only row
// i -> no cross-block hazard. row = blockIdx.x in [0,B*S).
// ---------------------------------------------------------------------------
template <bool CAUSAL>
__global__ __launch_bounds__(256) void softmax_kernel(
    const float* sc, bf16_t* p) {
  const int row = blockIdx.x;
  const int len = CAUSAL ? (row & (SDIM - 1)) + 1 : SDIM;
  const int t = threadIdx.x;
  const float4* srow = (const float4*)(sc + (size_t)row * SDIM);
  const float4 a = srow[t];
  const float4 b = srow[t + 256];
  const int c0 = t * 4, c1 = 1024 + t * 4;
  float xa[4] = {a.x, a.y, a.z, a.w};
  float xb[4] = {b.x, b.y, b.z, b.w};
#pragma unroll
  for (int i = 0; i < 4; ++i) {
    if (c0 + i >= len) xa[i] = -1e30f;
    if (c1 + i >= len) xb[i] = -1e30f;
  }
  float mx = fmaxf(fmaxf(fmaxf(xa[0], xa[1]), fmaxf(xa[2], xa[3])),
                   fmaxf(fmaxf(xb[0], xb[1]), fmaxf(xb[2], xb[3])));
#pragma unroll
  for (int o = 32; o > 0; o >>= 1) mx = fmaxf(mx, __shfl_xor(mx, o, 64));
  __shared__ float red[4];
  const int wid = t >> 6;
  if ((t & 63) == 0) red[wid] = mx;
  __syncthreads();
  mx = fmaxf(fmaxf(red[0], red[1]), fmaxf(red[2], red[3]));
  __syncthreads();
  float sm = 0.0f;
#pragma unroll
  for (int i = 0; i < 4; ++i) {
    xa[i] = __expf(xa[i] - mx);
    xb[i] = __expf(xb[i] - mx);
    sm += xa[i] + xb[i];
  }
#pragma unroll
  for (int o = 32; o > 0; o >>= 1) sm += __shfl_xor(sm, o, 64);
  if ((t & 63) == 0) red[wid] = sm;
  __syncthreads();
  sm = red[0] + red[1] + red[2] + red[3];
  const float inv = 1.0f / sm;
  ushort4 o0, o1;
  o0.x = bfbits(xa[0] * inv);
  o0.y = bfbits(xa[1] * inv);
  o0.z = bfbits(xa[2] * inv);
  o0.w = bfbits(xa[3] * inv);
  o1.x = bfbits(xb[0] * inv);
  o1.y = bfbits(xb[1] * inv);
  o1.z = bfbits(xb[2] * inv);
  o1.w = bfbits(xb[3] * inv);
  ushort4* prow = (ushort4*)(p + (size_t)row * PLD);
  prow[t] = o0;
  prow[t + 256] = o1;
}

// ---------------------------------------------------------------------------
// bf16 transpose per batch: in [R][C] (leading dim ldin) -> out [C][R]
// ---------------------------------------------------------------------------
__global__ __launch_bounds__(256) void transpose_bf16(
    const bf16_t* __restrict__ in, bf16_t* __restrict__ out, int R, int C,
    int ldin, long long sIn, long long sOut) {
  __shared__ bf16_t tile[32][33];
  const bf16_t* ip = in + (size_t)blockIdx.z * sIn;
  bf16_t* op = out + (size_t)blockIdx.z * sOut;
  const int r0 = blockIdx.y * 32, c0 = blockIdx.x * 32;
  const int tx = threadIdx.x & 31, ty = threadIdx.x >> 5;  // ty 0..7
#pragma unroll
  for (int i = 0; i < 32; i += 8)
    tile[ty + i][tx] = ip[(size_t)(r0 + ty + i) * ldin + c0 + tx];
  __syncthreads();
#pragma unroll
  for (int i = 0; i < 32; i += 8)
    op[(size_t)(c0 + ty + i) * R + r0 + tx] = tile[tx][ty + i];
}

// ---------------------------------------------------------------------------
// fp32 -> bf16 cast, float4-vectorized grid-stride
// ---------------------------------------------------------------------------
__global__ __launch_bounds__(256) void cvt_f32_bf16(const float* __restrict__ in,
                                                    bf16_t* __restrict__ out,
                                                    int n4) {
  int i = blockIdx.x * 256 + threadIdx.x;
  const int stride = gridDim.x * 256;
  for (; i < n4; i += stride) {
    const float4 v = ((const float4*)in)[i];
    ushort4 o;
    o.x = bfbits(v.x);
    o.y = bfbits(v.y);
    o.z = bfbits(v.z);
    o.w = bfbits(v.w);
    ((ushort4*)out)[i] = o;
  }
}

// 8 E*E fp32 matrices -> contiguous bf16 dst (blockIdx.y = matrix index)
struct Ptr8 {
  const float* p[8];
};
__global__ __launch_bounds__(256) void cvt8_f32_bf16(Ptr8 srcs,
                                                     bf16_t* __restrict__ dst) {
  const int m = blockIdx.y;
  const float* in = srcs.p[m];
  bf16_t* out = dst + (size_t)m * EDIM * EDIM;
  const int n4 = EDIM * EDIM / 4;
  int i = blockIdx.x * 256 + threadIdx.x;
  const int stride = gridDim.x * 256;
  for (; i < n4; i += stride) {
    const float4 v = ((const float4*)in)[i];
    ushort4 o;
    o.x = bfbits(v.x);
    o.y = bfbits(v.y);
    o.z = bfbits(v.z);
    o.w = bfbits(v.w);
    ((ushort4*)out)[i] = o;
  }
}

// pack up to 3 fp32 bias vectors of length n into dst
__global__ void pack_bias(const float* a, const float* b, const float* c,
                          float* dst, int n) {
  int i = blockIdx.x * 256 + threadIdx.x;
  int total = c ? 3 * n : 2 * n;
  if (i >= total) return;
  const float* src = (i < n) ? a : (i < 2 * n ? b : c);
  dst[i] = src[i % n];
}

// ---------------------------------------------------------------------------
extern "C" void kernel_launch(void* const* d_in, const int* in_sizes, int n_in,
                              void* d_out, int out_size, void* d_ws,
                              size_t ws_size, hipStream_t stream) {
  (void)in_sizes;
  (void)n_in;
  (void)out_size;
  (void)ws_size;
  const float* src_encs = (const float*)d_in[0];
  const float* tgt = (const float*)d_in[1];
  const float* ln1_g = (const float*)d_in[2];
  const float* ln1_b = (const float*)d_in[3];
  const float* ln2_g = (const float*)d_in[4];
  const float* ln2_b = (const float*)d_in[5];
  const float* ln3_g = (const float*)d_in[6];
  const float* ln3_b = (const float*)d_in[7];
  const float* sa_Wq = (const float*)d_in[8];
  const float* sa_bq = (const float*)d_in[9];
  const float* sa_Wk = (const float*)d_in[10];
  const float* sa_bk = (const float*)d_in[11];
  const float* sa_Wv = (const float*)d_in[12];
  const float* sa_bv = (const float*)d_in[13];
  const float* sa_Wo = (const float*)d_in[14];
  const float* sa_bo = (const float*)d_in[15];
  const float* ca_Wq = (const float*)d_in[16];
  const float* ca_bq = (const float*)d_in[17];
  const float* ca_Wk = (const float*)d_in[18];
  const float* ca_bk = (const float*)d_in[19];
  const float* ca_Wv = (const float*)d_in[20];
  const float* ca_bv = (const float*)d_in[21];
  const float* ca_Wo = (const float*)d_in[22];
  const float* ca_bo = (const float*)d_in[23];
  const float* ff_W1 = (const float*)d_in[24];
  const float* ff_b1 = (const float*)d_in[25];
  const float* ff_W2 = (const float*)d_in[26];
  const float* ff_b2 = (const float*)d_in[27];
  float* out = (float*)d_out;

  // resid lives in d_out (fully rewritten by self-attn Wo before any read).
  float* resid = out;

  // ---- workspace carve-up: ~192 MB ----
  char* w = (char*)d_ws;
  auto take = [&](size_t bytes) {
    void* pp = (void*)w;
    w += (bytes + 255) & ~(size_t)255;
    return pp;
  };
  const size_t TE_BF = (size_t)MTOK * EDIM * 2;    // 16 MB
  const size_t EE2 = (size_t)EDIM * EDIM * 2;      // 2 MB

  bf16_t* xn = (bf16_t*)take(TE_BF);                         // 16
  bf16_t* qkv = (bf16_t*)take((size_t)MTOK * 3 * EDIM * 2);  // 48, ld 3072
  bf16_t* vt = (bf16_t*)take(TE_BF);                         // 16 [B][E][S]
  bf16_t* srcb = (bf16_t*)take(TE_BF);                       // 16
  float* sc = (float*)take((size_t)BDIM * SDIM * SDIM * 4);  // 64 fp32 scores
  // 8 contiguous E*E bf16 weight slots (one fused cast launch):
  //   [0..2] wqkv  [3] cwq  [4..5] cwkv  [6] wo  [7] cwo
  bf16_t* w8 = (bf16_t*)take(8 * EE2);
  bf16_t* wqkv = w8;
  bf16_t* cwq = w8 + 3 * EDIM * EDIM;
  bf16_t* cwkv = w8 + 4 * EDIM * EDIM;
  bf16_t* wo = w8 + 6 * EDIM * EDIM;
  bf16_t* cwo = w8 + 7 * EDIM * EDIM;
  bf16_t* w1 = (bf16_t*)take((size_t)FDIM * EDIM * 2);  // 8
  bf16_t* w2 = (bf16_t*)take((size_t)EDIM * FDIM * 2);  // 8
  float* bqkv = (float*)take(3 * EDIM * 4);
  float* cbkv = (float*)take(2 * EDIM * 4);
  // Row-interleaved reuse of the 64MB sc region (8KB per row gr):
  //   bytes [0,4KB):   probs pbx, bf16 ld PLD=4096  (written by softmax)
  //   bytes [4KB,6KB): attn-out aox, bf16 ld PLD    (written by PV GEMM)
  // PV reads probs [0,4KB) and writes ao [4KB,6KB) -> disjoint, race-free.
  bf16_t* pbx = (bf16_t*)sc;
  bf16_t* aox = (bf16_t*)sc + 2048;
  // FFN hidden h (64MB) reuses the whole region after attention is done.
  bf16_t* h = (bf16_t*)sc;

  const int FE4 = FDIM * EDIM / 4;
  Ptr8 w8src;
  w8src.p[0] = sa_Wq;
  w8src.p[1] = sa_Wk;
  w8src.p[2] = sa_Wv;
  w8src.p[3] = ca_Wq;
  w8src.p[4] = ca_Wk;
  w8src.p[5] = ca_Wv;
  w8src.p[6] = sa_Wo;
  w8src.p[7] = ca_Wo;
  cvt8_f32_bf16<<<dim3(256, 8), 256, 0, stream>>>(w8src, w8);
  cvt_f32_bf16<<<2048, 256, 0, stream>>>(ff_W1, w1, FE4);
  cvt_f32_bf16<<<2048, 256, 0, stream>>>(ff_W2, w2, FE4);
  cvt_f32_bf16<<<2048, 256, 0, stream>>>(src_encs, srcb, MTOK * EDIM / 4);
  pack_bias<<<12, 256, 0, stream>>>(sa_bq, sa_bk, sa_bv, bqkv, EDIM);
  pack_bias<<<8, 256, 0, stream>>>(ca_bk, ca_bv, nullptr, cbkv, EDIM);

  const int LQKV = 3 * EDIM;                      // 3072
  const long long sQ = (long long)SDIM * LQKV;    // per-batch qkv stride
  const long long sS = (long long)SDIM * SDIM;    // per-batch scores stride
  const long long sP = (long long)SDIM * PLD;     // per-batch probs/ao stride
  const long long sVT = (long long)EDIM * SDIM;   // per-batch Vt stride
  const float asc = 0.03125f;                     // 1/sqrt(1024)

  // ---- self attention ----
  ln_kernel<<<MTOK, 256, 0, stream>>>(tgt, ln1_g, ln1_b, xn);
  // fused QKV projection: [8192][3072]  (1536 blocks -> 4/CU, no DBUF)
  gemm_nt<bf16_t, true, false, false, false, false, false>
      <<<dim3(24, 64, 1), 256, 0, stream>>>(xn, wqkv, bqkv, nullptr, qkv,
                                            LQKV, EDIM, EDIM, EDIM, LQKV,
                                            0, 0, 0, 1.0f);
  transpose_bf16<<<dim3(32, 64, BDIM), 256, 0, stream>>>(
      qkv + 2 * EDIM, vt, SDIM, EDIM, LQKV, sQ, sVT);
  // self scores (544 active blocks -> ~2/CU, DBUF)
  gemm_nt<float, false, false, false, true, false, true>
      <<<dim3(16, 16, BDIM), 256, 0, stream>>>(qkv, qkv + EDIM, nullptr,
                                               nullptr, sc, SDIM, EDIM, LQKV,
                                               LQKV, SDIM, sQ, sQ, sS, asc);
  softmax_kernel<true><<<MTOK, 256, 0, stream>>>(sc, pbx);
  // self PV (512 blocks, DBUF)
  gemm_nt<bf16_t, false, false, false, false, true, true>
      <<<dim3(8, 16, BDIM), 256, 0, stream>>>(pbx, vt, nullptr, nullptr, aox,
                                              EDIM, SDIM, PLD, SDIM, PLD,
                                              sP, sVT, sP, 1.0f);
  // self Wo + residual (512 blocks, DBUF)
  gemm_nt<float, true, true, false, false, false, true>
      <<<dim3(8, 64, 1), 256, 0, stream>>>(aox, wo, sa_bo, tgt, resid, EDIM,
                                           EDIM, PLD, EDIM, EDIM, 0, 0, 0,
                                           1.0f);

  // ---- cross attention ----
  ln_kernel<<<MTOK, 256, 0, stream>>>(resid, ln2_g, ln2_b, xn);
  // cross Q (512 blocks, DBUF)
  gemm_nt<bf16_t, true, false, false, false, false, true>
      <<<dim3(8, 64, 1), 256, 0, stream>>>(xn, cwq, ca_bq, nullptr, qkv,
                                           EDIM, EDIM, EDIM, EDIM, LQKV,
                                           0, 0, 0, 1.0f);
  // cross K/V fused (1024 blocks -> 4/CU, no DBUF)
  gemm_nt<bf16_t, true, false, false, false, false, false>
      <<<dim3(16, 64, 1), 256, 0, stream>>>(srcb, cwkv, cbkv, nullptr,
                                            qkv + EDIM, 2 * EDIM, EDIM, EDIM,
                                            EDIM, LQKV, 0, 0, 0, 1.0f);
  transpose_bf16<<<dim3(32, 64, BDIM), 256, 0, stream>>>(
      qkv + 2 * EDIM, vt, SDIM, EDIM, LQKV, sQ, sVT);
  // cross scores (1024 blocks -> 4/CU, no DBUF)
  gemm_nt<float, false, false, false, false, false, false>
      <<<dim3(16, 16, BDIM), 256, 0, stream>>>(qkv, qkv + EDIM, nullptr,
                                               nullptr, sc, SDIM, EDIM, LQKV,
                                               LQKV, SDIM, sQ, sQ, sS, asc);
  softmax_kernel<false><<<MTOK, 256, 0, stream>>>(sc, pbx);
  // cross PV (512 blocks, DBUF)
  gemm_nt<bf16_t, false, false, false, false, false, true>
      <<<dim3(8, 16, BDIM), 256, 0, stream>>>(pbx, vt, nullptr, nullptr, aox,
                                              EDIM, SDIM, PLD, SDIM, PLD,
                                              sP, sVT, sP, 1.0f);
  // cross Wo + residual in-place (512 blocks, DBUF)
  gemm_nt<float, true, true, false, false, false, true>
      <<<dim3(8, 64, 1), 256, 0, stream>>>(aox, cwo, ca_bo, resid, resid,
                                           EDIM, EDIM, PLD, EDIM, EDIM, 0, 0,
                                           0, 1.0f);

  // ---- feed forward ----
  ln_kernel<<<MTOK, 256, 0, stream>>>(resid, ln3_g, ln3_b, xn);
  // FF1 (2048 blocks -> 4/CU, no DBUF)
  gemm_nt<bf16_t, true, false, true, false, false, false>
      <<<dim3(32, 64, 1), 256, 0, stream>>>(xn, w1, ff_b1, nullptr, h, FDIM,
                                            EDIM, EDIM, EDIM, FDIM, 0, 0, 0,
                                            1.0f);
  // FF2 + residual (512 blocks, DBUF)
  gemm_nt<float, true, true, false, false, false, true>
      <<<dim3(8, 64, 1), 256, 0, stream>>>(h, w2, ff_b2, resid, out, EDIM,
                                           FDIM, FDIM, FDIM, EDIM, 0, 0, 0,
                                           1.0f);
}

// Round 12
// 923.450 us; speedup vs baseline: 1.0509x; 1.0509x over previous
//
#include <hip/hip_runtime.h>
#include <hip/hip_bf16.h>
#include <cstdint>
#include <cstddef>

#define EDIM 1024
#define FDIM 4096
#define BDIM 4
#define SDIM 2048
#define MTOK (BDIM * SDIM)   // 8192 token rows
#define PLD 4096             // bf16 leading dim inside the 8KB fp32 score rows

typedef __bf16 bf16_t;
typedef __bf16 bf16x8 __attribute__((ext_vector_type(8)));
typedef float f32x4 __attribute__((ext_vector_type(4)));

__device__ __forceinline__ void gload_lds16(const void* g, void* l) {
  __builtin_amdgcn_global_load_lds(
      (const __attribute__((address_space(1))) void*)g,
      (__attribute__((address_space(3))) void*)l, 16, 0, 0);
}

__device__ __forceinline__ unsigned short bfbits(float f) {
  bf16_t h = (bf16_t)f;
  return __builtin_bit_cast(unsigned short, h);
}

// m204 bijective XCD remap of the flattened grid id (8 XCDs on MI355X).
// Pure permutation of blocks -> correctness-independent of HW mapping.
// Round-8 A/B arithmetic: swizzle cut FF2 FETCH 282->82 MB (~ -100us total);
// keep. The DBUF single-barrier loop cost +150us (MfmaUtil 24->19%); reverted.
__device__ __forceinline__ void xcd_remap(int& bx, int& by, int& bz) {
  const int gx = gridDim.x, gy = gridDim.y;
  const int nwg = gx * gy * gridDim.z;
  int id = blockIdx.x + gx * (blockIdx.y + gy * blockIdx.z);
  const int q = nwg >> 3, r = nwg & 7;
  const int xcd = id & 7, off = id >> 3;
  id = (xcd < r ? xcd * (q + 1) : r * (q + 1) + (xcd - r) * q) + off;
  bx = id % gx;
  const int t = id / gx;
  by = t % gy;
  bz = t / gy;
}

// ---------------------------------------------------------------------------
// NT GEMM: C[M,N] = alpha * A[M,K] @ B[N,K]^T (+bias) (+res) (+relu)
// A, B bf16 row-major (K-contiguous, arbitrary leading dim). 128x128 tile,
// BK=64, 4 waves (2x2), each wave 64x64 via 4x4 frags of 16x16x32 MFMA.
// m97-style: global_load_lds width-16 staging, linear LDS, 2-barrier loop
// (proven 924us baseline structure; r8 showed 1-barrier dbuf regresses at
// 2 blocks/CU -- the 2-barrier loop lets co-resident blocks desync+overlap).
// z-grid batches with strides sA/sB/sC. CSKIP: skip blocks above causal
// diagonal. CKLIM: clamp K-loop to m0+128 (PV with causal-zeroed P).
// res/C not __restrict__: used in-place (res==C), 1 reader/writer per elem.
// ---------------------------------------------------------------------------
template <typename OutT, bool BIAS, bool RES, bool RELU, bool CSKIP, bool CKLIM>
__global__ __launch_bounds__(256, 2) void gemm_nt(
    const bf16_t* __restrict__ A, const bf16_t* __restrict__ Bm,
    const float* __restrict__ bias, const float* res,
    OutT* C, int N, int K, int lda, int ldb, int ldc,
    long long sA, long long sB, long long sC, float alpha) {
  int bn, bm, bz;
  xcd_remap(bn, bm, bz);
  const int m0 = bm * 128, n0 = bn * 128;
  if constexpr (CSKIP) {
    if (n0 > m0 + 127) return;
  }
  A += (size_t)bz * sA;
  Bm += (size_t)bz * sB;
  C += (size_t)bz * sC;

  __shared__ __align__(16) bf16_t As[128][64];
  __shared__ __align__(16) bf16_t Bs[128][64];

  const int tid = threadIdx.x;
  const int lane = tid & 63;
  const int wid = tid >> 6;
  const int wr = (wid >> 1) * 64;  // wave row offset in tile
  const int wc = (wid & 1) * 64;   // wave col offset in tile
  const int lr = lane & 15;        // fragment row/col
  const int lk = (lane >> 4) * 8;  // fragment k offset

  f32x4 acc[4][4] = {};

  int Keff = K;
  if constexpr (CKLIM) {
    const int kl = m0 + 128;
    Keff = kl < K ? kl : K;
  }
  const int nkt = Keff >> 6;

  // staging: 128x64 bf16 tile; wave-uniform LDS base + lane*16B (m104 rule)
  const int se = tid * 8;     // element offset within tile (row-major)
  const int sr = se >> 6;     // row 0..31
  const int sc = se & 63;     // col (multiple of 8)

  for (int kt = 0; kt < nkt; ++kt) {
    const int k0 = kt << 6;
    const bf16_t* Ag = A + (size_t)(m0 + sr) * lda + k0 + sc;
    const bf16_t* Bg = Bm + (size_t)(n0 + sr) * ldb + k0 + sc;
#pragma unroll
    for (int it = 0; it < 4; ++it) {
      gload_lds16(Ag + (size_t)it * 32 * lda, &As[sr + it * 32][sc]);
      gload_lds16(Bg + (size_t)it * 32 * ldb, &Bs[sr + it * 32][sc]);
    }
    __syncthreads();
#pragma unroll
    for (int kk = 0; kk < 2; ++kk) {
      bf16x8 af[4], bfr[4];
#pragma unroll
      for (int i = 0; i < 4; ++i)
        af[i] = *(const bf16x8*)&As[wr + i * 16 + lr][kk * 32 + lk];
#pragma unroll
      for (int i = 0; i < 4; ++i)
        bfr[i] = *(const bf16x8*)&Bs[wc + i * 16 + lr][kk * 32 + lk];
#pragma unroll
      for (int mi = 0; mi < 4; ++mi)
#pragma unroll
        for (int ni = 0; ni < 4; ++ni)
          acc[mi][ni] = __builtin_amdgcn_mfma_f32_16x16x32_bf16(
              af[mi], bfr[ni], acc[mi][ni], 0, 0, 0);
    }
    __syncthreads();
  }

  // epilogue: C/D layout col=lane&15, row=(lane>>4)*4+reg  [m89/m91]
  const int rbase = (lane >> 4) * 4;
#pragma unroll
  for (int mi = 0; mi < 4; ++mi) {
#pragma unroll
    for (int ni = 0; ni < 4; ++ni) {
      const int gc = n0 + wc + ni * 16 + lr;
      float bv = 0.0f;
      if constexpr (BIAS) bv = bias[gc];
#pragma unroll
      for (int j = 0; j < 4; ++j) {
        const int gr = m0 + wr + mi * 16 + rbase + j;
        float v = acc[mi][ni][j] * alpha + bv;
        if constexpr (RES) v += res[(size_t)gr * ldc + gc];
        if constexpr (RELU) v = fmaxf(v, 0.0f);
        C[(size_t)gr * ldc + gc] = (OutT)v;
      }
    }
  }
}

// ---------------------------------------------------------------------------
// LayerNorm over last dim (E=1024), fp32 in -> bf16 out. 1 block / row.
// ---------------------------------------------------------------------------
__global__ __launch_bounds__(256) void ln_kernel(const float* __restrict__ x,
                                                 const float* __restrict__ g,
                                                 const float* __restrict__ be,
                                                 bf16_t* __restrict__ y) {
  const int row = blockIdx.x;
  const int t = threadIdx.x;
  const float4 v = ((const float4*)(x + (size_t)row * EDIM))[t];
  float s = v.x + v.y + v.z + v.w;
  float s2 = v.x * v.x + v.y * v.y + v.z * v.z + v.w * v.w;
#pragma unroll
  for (int o = 32; o > 0; o >>= 1) {
    s += __shfl_xor(s, o, 64);
    s2 += __shfl_xor(s2, o, 64);
  }
  __shared__ float red[8];
  const int wid = t >> 6;
  if ((t & 63) == 0) {
    red[wid] = s;
    red[4 + wid] = s2;
  }
  __syncthreads();
  s = red[0] + red[1] + red[2] + red[3];
  s2 = red[4] + red[5] + red[6] + red[7];
  const float mu = s * (1.0f / EDIM);
  const float var = s2 * (1.0f / EDIM) - mu * mu;
  const float rs = rsqrtf(var + 1e-5f);
  const float4 gg = ((const float4*)g)[t];
  const float4 bb = ((const float4*)be)[t];
  ushort4 o4;
  o4.x = bfbits((v.x - mu) * rs * gg.x + bb.x);
  o4.y = bfbits((v.y - mu) * rs * gg.y + bb.y);
  o4.z = bfbits((v.z - mu) * rs * gg.z + bb.z);
  o4.w = bfbits((v.w - mu) * rs * gg.w + bb.w);
  ((ushort4*)(y + (size_t)row * EDIM))[t] = o4;
}

// ---------------------------------------------------------------------------
// Row softmax over S=2048 cols, fp32 scores -> bf16 probs written IN-PLACE
// into the first 4KB of the same 8KB score row (bf16 ld PLD=4096). All
// score reads are in registers before the writes; block i touches only row
// i -> no cross-block hazard. row = blockIdx.x in [0,B*S).
// ---------------------------------------------------------------------------
template <bool CAUSAL>
__global__ __launch_bounds__(256) void softmax_kernel(
    const float* sc, bf16_t* p) {
  const int row = blockIdx.x;
  const int len = CAUSAL ? (row & (SDIM - 1)) + 1 : SDIM;
  const int t = threadIdx.x;
  const float4* srow = (const float4*)(sc + (size_t)row * SDIM);
  const float4 a = srow[t];
  const float4 b = srow[t + 256];
  const int c0 = t * 4, c1 = 1024 + t * 4;
  float xa[4] = {a.x, a.y, a.z, a.w};
  float xb[4] = {b.x, b.y, b.z, b.w};
#pragma unroll
  for (int i = 0; i < 4; ++i) {
    if (c0 + i >= len) xa[i] = -1e30f;
    if (c1 + i >= len) xb[i] = -1e30f;
  }
  float mx = fmaxf(fmaxf(fmaxf(xa[0], xa[1]), fmaxf(xa[2], xa[3])),
                   fmaxf(fmaxf(xb[0], xb[1]), fmaxf(xb[2], xb[3])));
#pragma unroll
  for (int o = 32; o > 0; o >>= 1) mx = fmaxf(mx, __shfl_xor(mx, o, 64));
  __shared__ float red[4];
  const int wid = t >> 6;
  if ((t & 63) == 0) red[wid] = mx;
  __syncthreads();
  mx = fmaxf(fmaxf(red[0], red[1]), fmaxf(red[2], red[3]));
  __syncthreads();
  float sm = 0.0f;
#pragma unroll
  for (int i = 0; i < 4; ++i) {
    xa[i] = __expf(xa[i] - mx);
    xb[i] = __expf(xb[i] - mx);
    sm += xa[i] + xb[i];
  }
#pragma unroll
  for (int o = 32; o > 0; o >>= 1) sm += __shfl_xor(sm, o, 64);
  if ((t & 63) == 0) red[wid] = sm;
  __syncthreads();
  sm = red[0] + red[1] + red[2] + red[3];
  const float inv = 1.0f / sm;
  ushort4 o0, o1;
  o0.x = bfbits(xa[0] * inv);
  o0.y = bfbits(xa[1] * inv);
  o0.z = bfbits(xa[2] * inv);
  o0.w = bfbits(xa[3] * inv);
  o1.x = bfbits(xb[0] * inv);
  o1.y = bfbits(xb[1] * inv);
  o1.z = bfbits(xb[2] * inv);
  o1.w = bfbits(xb[3] * inv);
  ushort4* prow = (ushort4*)(p + (size_t)row * PLD);
  prow[t] = o0;
  prow[t + 256] = o1;
}

// ---------------------------------------------------------------------------
// bf16 transpose per batch: in [R][C] (leading dim ldin) -> out [C][R]
// ---------------------------------------------------------------------------
__global__ __launch_bounds__(256) void transpose_bf16(
    const bf16_t* __restrict__ in, bf16_t* __restrict__ out, int R, int C,
    int ldin, long long sIn, long long sOut) {
  __shared__ bf16_t tile[32][33];
  const bf16_t* ip = in + (size_t)blockIdx.z * sIn;
  bf16_t* op = out + (size_t)blockIdx.z * sOut;
  const int r0 = blockIdx.y * 32, c0 = blockIdx.x * 32;
  const int tx = threadIdx.x & 31, ty = threadIdx.x >> 5;  // ty 0..7
#pragma unroll
  for (int i = 0; i < 32; i += 8)
    tile[ty + i][tx] = ip[(size_t)(r0 + ty + i) * ldin + c0 + tx];
  __syncthreads();
#pragma unroll
  for (int i = 0; i < 32; i += 8)
    op[(size_t)(c0 + ty + i) * R + r0 + tx] = tile[tx][ty + i];
}

// ---------------------------------------------------------------------------
// fp32 -> bf16 cast, float4-vectorized grid-stride
// ---------------------------------------------------------------------------
__global__ __launch_bounds__(256) void cvt_f32_bf16(const float* __restrict__ in,
                                                    bf16_t* __restrict__ out,
                                                    int n4) {
  int i = blockIdx.x * 256 + threadIdx.x;
  const int stride = gridDim.x * 256;
  for (; i < n4; i += stride) {
    const float4 v = ((const float4*)in)[i];
    ushort4 o;
    o.x = bfbits(v.x);
    o.y = bfbits(v.y);
    o.z = bfbits(v.z);
    o.w = bfbits(v.w);
    ((ushort4*)out)[i] = o;
  }
}

// 8 E*E fp32 matrices -> contiguous bf16 dst (blockIdx.y = matrix index)
struct Ptr8 {
  const float* p[8];
};
__global__ __launch_bounds__(256) void cvt8_f32_bf16(Ptr8 srcs,
                                                     bf16_t* __restrict__ dst) {
  const int m = blockIdx.y;
  const float* in = srcs.p[m];
  bf16_t* out = dst + (size_t)m * EDIM * EDIM;
  const int n4 = EDIM * EDIM / 4;
  int i = blockIdx.x * 256 + threadIdx.x;
  const int stride = gridDim.x * 256;
  for (; i < n4; i += stride) {
    const float4 v = ((const float4*)in)[i];
    ushort4 o;
    o.x = bfbits(v.x);
    o.y = bfbits(v.y);
    o.z = bfbits(v.z);
    o.w = bfbits(v.w);
    ((ushort4*)out)[i] = o;
  }
}

// pack up to 3 fp32 bias vectors of length n into dst
__global__ void pack_bias(const float* a, const float* b, const float* c,
                          float* dst, int n) {
  int i = blockIdx.x * 256 + threadIdx.x;
  int total = c ? 3 * n : 2 * n;
  if (i >= total) return;
  const float* src = (i < n) ? a : (i < 2 * n ? b : c);
  dst[i] = src[i % n];
}

// ---------------------------------------------------------------------------
extern "C" void kernel_launch(void* const* d_in, const int* in_sizes, int n_in,
                              void* d_out, int out_size, void* d_ws,
                              size_t ws_size, hipStream_t stream) {
  (void)in_sizes;
  (void)n_in;
  (void)out_size;
  (void)ws_size;
  const float* src_encs = (const float*)d_in[0];
  const float* tgt = (const float*)d_in[1];
  const float* ln1_g = (const float*)d_in[2];
  const float* ln1_b = (const float*)d_in[3];
  const float* ln2_g = (const float*)d_in[4];
  const float* ln2_b = (const float*)d_in[5];
  const float* ln3_g = (const float*)d_in[6];
  const float* ln3_b = (const float*)d_in[7];
  const float* sa_Wq = (const float*)d_in[8];
  const float* sa_bq = (const float*)d_in[9];
  const float* sa_Wk = (const float*)d_in[10];
  const float* sa_bk = (const float*)d_in[11];
  const float* sa_Wv = (const float*)d_in[12];
  const float* sa_bv = (const float*)d_in[13];
  const float* sa_Wo = (const float*)d_in[14];
  const float* sa_bo = (const float*)d_in[15];
  const float* ca_Wq = (const float*)d_in[16];
  const float* ca_bq = (const float*)d_in[17];
  const float* ca_Wk = (const float*)d_in[18];
  const float* ca_bk = (const float*)d_in[19];
  const float* ca_Wv = (const float*)d_in[20];
  const float* ca_bv = (const float*)d_in[21];
  const float* ca_Wo = (const float*)d_in[22];
  const float* ca_bo = (const float*)d_in[23];
  const float* ff_W1 = (const float*)d_in[24];
  const float* ff_b1 = (const float*)d_in[25];
  const float* ff_W2 = (const float*)d_in[26];
  const float* ff_b2 = (const float*)d_in[27];
  float* out = (float*)d_out;

  // resid lives in d_out (fully rewritten by self-attn Wo before any read).
  float* resid = out;

  // ---- workspace carve-up: ~192 MB ----
  char* w = (char*)d_ws;
  auto take = [&](size_t bytes) {
    void* pp = (void*)w;
    w += (bytes + 255) & ~(size_t)255;
    return pp;
  };
  const size_t TE_BF = (size_t)MTOK * EDIM * 2;    // 16 MB
  const size_t EE2 = (size_t)EDIM * EDIM * 2;      // 2 MB

  bf16_t* xn = (bf16_t*)take(TE_BF);                         // 16
  bf16_t* qkv = (bf16_t*)take((size_t)MTOK * 3 * EDIM * 2);  // 48, ld 3072
  bf16_t* vt = (bf16_t*)take(TE_BF);                         // 16 [B][E][S]
  bf16_t* srcb = (bf16_t*)take(TE_BF);                       // 16
  float* sc = (float*)take((size_t)BDIM * SDIM * SDIM * 4);  // 64 fp32 scores
  // 8 contiguous E*E bf16 weight slots (one fused cast launch):
  //   [0..2] wqkv  [3] cwq  [4..5] cwkv  [6] wo  [7] cwo
  bf16_t* w8 = (bf16_t*)take(8 * EE2);
  bf16_t* wqkv = w8;
  bf16_t* cwq = w8 + 3 * EDIM * EDIM;
  bf16_t* cwkv = w8 + 4 * EDIM * EDIM;
  bf16_t* wo = w8 + 6 * EDIM * EDIM;
  bf16_t* cwo = w8 + 7 * EDIM * EDIM;
  bf16_t* w1 = (bf16_t*)take((size_t)FDIM * EDIM * 2);  // 8
  bf16_t* w2 = (bf16_t*)take((size_t)EDIM * FDIM * 2);  // 8
  float* bqkv = (float*)take(3 * EDIM * 4);
  float* cbkv = (float*)take(2 * EDIM * 4);
  // Row-interleaved reuse of the 64MB sc region (8KB per row gr):
  //   bytes [0,4KB):   probs pbx, bf16 ld PLD=4096  (written by softmax)
  //   bytes [4KB,6KB): attn-out aox, bf16 ld PLD    (written by PV GEMM)
  // PV reads probs [0,4KB) and writes ao [4KB,6KB) -> disjoint, race-free.
  bf16_t* pbx = (bf16_t*)sc;
  bf16_t* aox = (bf16_t*)sc + 2048;
  // FFN hidden h (64MB) reuses the whole region after attention is done.
  bf16_t* h = (bf16_t*)sc;

  const int FE4 = FDIM * EDIM / 4;
  Ptr8 w8src;
  w8src.p[0] = sa_Wq;
  w8src.p[1] = sa_Wk;
  w8src.p[2] = sa_Wv;
  w8src.p[3] = ca_Wq;
  w8src.p[4] = ca_Wk;
  w8src.p[5] = ca_Wv;
  w8src.p[6] = sa_Wo;
  w8src.p[7] = ca_Wo;
  cvt8_f32_bf16<<<dim3(256, 8), 256, 0, stream>>>(w8src, w8);
  cvt_f32_bf16<<<2048, 256, 0, stream>>>(ff_W1, w1, FE4);
  cvt_f32_bf16<<<2048, 256, 0, stream>>>(ff_W2, w2, FE4);
  cvt_f32_bf16<<<2048, 256, 0, stream>>>(src_encs, srcb, MTOK * EDIM / 4);
  pack_bias<<<12, 256, 0, stream>>>(sa_bq, sa_bk, sa_bv, bqkv, EDIM);
  pack_bias<<<8, 256, 0, stream>>>(ca_bk, ca_bv, nullptr, cbkv, EDIM);

  const int LQKV = 3 * EDIM;                      // 3072
  const long long sQ = (long long)SDIM * LQKV;    // per-batch qkv stride
  const long long sS = (long long)SDIM * SDIM;    // per-batch scores stride
  const long long sP = (long long)SDIM * PLD;     // per-batch probs/ao stride
  const long long sVT = (long long)EDIM * SDIM;   // per-batch Vt stride
  const float asc = 0.03125f;                     // 1/sqrt(1024)

  // ---- self attention ----
  ln_kernel<<<MTOK, 256, 0, stream>>>(tgt, ln1_g, ln1_b, xn);
  // fused QKV projection: [8192][3072]
  gemm_nt<bf16_t, true, false, false, false, false>
      <<<dim3(24, 64, 1), 256, 0, stream>>>(xn, wqkv, bqkv, nullptr, qkv,
                                            LQKV, EDIM, EDIM, EDIM, LQKV,
                                            0, 0, 0, 1.0f);
  transpose_bf16<<<dim3(32, 64, BDIM), 256, 0, stream>>>(
      qkv + 2 * EDIM, vt, SDIM, EDIM, LQKV, sQ, sVT);
  gemm_nt<float, false, false, false, true, false>
      <<<dim3(16, 16, BDIM), 256, 0, stream>>>(qkv, qkv + EDIM, nullptr,
                                               nullptr, sc, SDIM, EDIM, LQKV,
                                               LQKV, SDIM, sQ, sQ, sS, asc);
  softmax_kernel<true><<<MTOK, 256, 0, stream>>>(sc, pbx);
  gemm_nt<bf16_t, false, false, false, false, true>
      <<<dim3(8, 16, BDIM), 256, 0, stream>>>(pbx, vt, nullptr, nullptr, aox,
                                              EDIM, SDIM, PLD, SDIM, PLD,
                                              sP, sVT, sP, 1.0f);
  gemm_nt<float, true, true, false, false, false>
      <<<dim3(8, 64, 1), 256, 0, stream>>>(aox, wo, sa_bo, tgt, resid, EDIM,
                                           EDIM, PLD, EDIM, EDIM, 0, 0, 0,
                                           1.0f);

  // ---- cross attention ----
  ln_kernel<<<MTOK, 256, 0, stream>>>(resid, ln2_g, ln2_b, xn);
  gemm_nt<bf16_t, true, false, false, false, false>
      <<<dim3(8, 64, 1), 256, 0, stream>>>(xn, cwq, ca_bq, nullptr, qkv,
                                           EDIM, EDIM, EDIM, EDIM, LQKV,
                                           0, 0, 0, 1.0f);
  gemm_nt<bf16_t, true, false, false, false, false>
      <<<dim3(16, 64, 1), 256, 0, stream>>>(srcb, cwkv, cbkv, nullptr,
                                            qkv + EDIM, 2 * EDIM, EDIM, EDIM,
                                            EDIM, LQKV, 0, 0, 0, 1.0f);
  transpose_bf16<<<dim3(32, 64, BDIM), 256, 0, stream>>>(
      qkv + 2 * EDIM, vt, SDIM, EDIM, LQKV, sQ, sVT);
  gemm_nt<float, false, false, false, false, false>
      <<<dim3(16, 16, BDIM), 256, 0, stream>>>(qkv, qkv + EDIM, nullptr,
                                               nullptr, sc, SDIM, EDIM, LQKV,
                                               LQKV, SDIM, sQ, sQ, sS, asc);
  softmax_kernel<false><<<MTOK, 256, 0, stream>>>(sc, pbx);
  gemm_nt<bf16_t, false, false, false, false, false>
      <<<dim3(8, 16, BDIM), 256, 0, stream>>>(pbx, vt, nullptr, nullptr, aox,
                                              EDIM, SDIM, PLD, SDIM, PLD,
                                              sP, sVT, sP, 1.0f);
  gemm_nt<float, true, true, false, false, false>
      <<<dim3(8, 64, 1), 256, 0, stream>>>(aox, cwo, ca_bo, resid, resid,
                                           EDIM, EDIM, PLD, EDIM, EDIM, 0, 0,
                                           0, 1.0f);

  // ---- feed forward ----
  ln_kernel<<<MTOK, 256, 0, stream>>>(resid, ln3_g, ln3_b, xn);
  gemm_nt<bf16_t, true, false, true, false, false>
      <<<dim3(32, 64, 1), 256, 0, stream>>>(xn, w1, ff_b1, nullptr, h, FDIM,
                                            EDIM, EDIM, EDIM, FDIM, 0, 0, 0,
                                            1.0f);
  gemm_nt<float, true, true, false, false, false>
      <<<dim3(8, 64, 1), 256, 0, stream>>>(h, w2, ff_b2, resid, out, EDIM,
                                           FDIM, FDIM, FDIM, EDIM, 0, 0, 0,
                                           1.0f);
}